// Round 8
// baseline (673.662 us; speedup 1.0000x reference)
//
#include <hip/hip_runtime.h>

typedef unsigned int u32;
typedef unsigned short u16;
typedef unsigned char u8;

#define NFR 8
#define NBX 1024
#define NTOT 8192     // 8*1024
#define NROW 7168     // 7*1024 adjacency rows
#define MAXS 48
#define NEGV -1000000000.0f
#define OVTOT 256     // total slot array size in iter kernel
#define OVPF 36       // per-frame slot budget (7*36 = 252 <= 256)
#define PSTRIDE 64    // pool u16 per listed row: [deg, j0..j_{deg-1}], deg<=63
#define DEG_RECOMP 0xFFFF
#define ENC_RESCAN  ((3u << 30) | (1023u << 10) | 1023u)

// d_ws layout in u32 units: csr[7168] | pool(8192) | ovl(128) | cnt(8)
#define WS_POOL 7168
#define WS_OVL  (7168 + 8192)
#define WS_OST2 (WS_OVL + 128)
#define WS_WORDS (WS_OST2 + 8)      // 15496 u32 = 61984 bytes

// Exact predicate IoU(a,b) >= 0.2 in f32, _rn ops in the reference's
// association order (area_a from 'a' first). Early exits are exact:
// wx<=0 or wy<=0  =>  inter==0 in the reference  =>  iou==0 < 0.2.
__device__ __forceinline__ bool iou_ge(const float4 a, const float4 b) {
    float wx = __fsub_rn(fminf(a.z, b.z), fmaxf(a.x, b.x));
    if (!(wx > 0.0f)) return false;
    float wy = __fsub_rn(fminf(a.w, b.w), fmaxf(a.y, b.y));
    if (!(wy > 0.0f)) return false;
    float inter = __fmul_rn(wx, wy);
    float aa = __fmul_rn(__fsub_rn(a.z, a.x), __fsub_rn(a.w, a.y));
    float ab = __fmul_rn(__fsub_rn(b.z, b.x), __fsub_rn(b.w, b.y));
    float den = __fadd_rn(__fsub_rn(__fadd_rn(aa, ab), inter), 1e-8f);
    return __fdiv_rn(inter, den) >= 0.2f;
}

// x-bin for interval pruning: 32 bins of width 3.5 over [-6, 106].
__device__ __forceinline__ int xbin(float x) {
    int b = (int)floorf(__fmul_rn(__fadd_rn(x, 6.0f), 0.2857142857f)); // 1/3.5
    return b < 0 ? 0 : (b > 31 ? 31 : b);
}

// csr row encoding (u32): top 2 bits = cnt.
//   inline (cnt<=3): (cnt<<30)|(j2<<20)|(j1<<10)|j0, ascending -> j0!=j1 if cnt==3
//   listed overflow: (3<<30)|(slot<<10)|slot, slot = f*OVPF + local < 252
//   rescan fallback: slot field == 1023 (per-frame budget exhausted; ~never)

// ============================ kernel 1: setup ============================
// (verified round-7 version, unchanged) 7 independent blocks, one per
// frame-pair, each writing its disjoint ws region.
__global__ __launch_bounds__(1024) void seqnms_setup(const float4* __restrict__ gbox,
                                                     const int* __restrict__ classes,
                                                     u32* __restrict__ ws) {
    __shared__ u32 clsb[3][32];     // class bitplanes, frame f+1 (pass 2 use)
    __shared__ u32 cmask[8][32];    // per-class word masks, frame f+1
    __shared__ u32 xbm[32][32];     // [word][bin] x-interval mask, frame f+1
    __shared__ u16 ovl_l[OVPF];
    __shared__ u32 ofill;

    const int f = blockIdx.x;       // 0..6
    const int t = threadIdx.x, gw = t >> 6, ln = t & 63;

    if (t < 32 * 32) ((u32*)xbm)[t] = 0;
    if (t < 256) ((u32*)cmask)[t] = 0;
    if (t < 96) ((u32*)clsb)[t] = 0;
    if (t == 0) ofill = 0;

    const float4 a4 = gbox[f * NBX + t];          // own row's box (frame f)
    const int ca = classes[f * NBX + t];
    const float4 nb4 = gbox[(f + 1) * NBX + t];   // own box in frame f+1
    const int ncl = classes[(f + 1) * NBX + t];
    __syncthreads();

    // ---- fill masks: one atomic pass over frame f+1 ----
    {
        const u32 bit = 1u << (t & 31); const int wrd = t >> 5;
        int b0 = xbin(nb4.x), b1 = xbin(nb4.z);
        for (int b = b0; b <= b1; ++b) atomicOr(&xbm[wrd][b], bit);
        atomicOr(&cmask[ncl][wrd], bit);
        if (ncl & 1) atomicOr(&clsb[0][wrd], bit);
        if (ncl & 2) atomicOr(&clsb[1][wrd], bit);
        if (ncl & 4) atomicOr(&clsb[2][wrd], bit);
    }
    __syncthreads();

    // ---- row scan (ascending j; exact predicate after superset filter) ----
    {
        const int rb0 = xbin(a4.x), rb1 = xbin(a4.z);
        const float4* nb = gbox + (f + 1) * NBX;
        u32 cnt = 0, j0 = 0, j1 = 0, j2 = 0;
        for (int w = 0; w < 32; ++w) {
            u32 mx = xbm[w][rb0];
            for (int b = rb0 + 1; b <= rb1; ++b) mx |= xbm[w][b];
            if (!mx) continue;
            u32 m = mx & cmask[ca][w];
            while (m) {
                int b = __ffs(m) - 1;
                m &= m - 1;
                int j = w * 32 + b;
                if (iou_ge(a4, nb[j])) {
                    if (cnt == 0) j0 = j; else if (cnt == 1) j1 = j; else if (cnt == 2) j2 = j;
                    ++cnt;
                }
            }
        }
        u32 enc;
        if (cnt <= 3) enc = (cnt << 30) | (j2 << 20) | (j1 << 10) | j0;
        else {
            u32 sl = atomicAdd(&ofill, 1u);
            if (sl < OVPF) {
                u32 slot = (u32)(f * OVPF) + sl;
                ovl_l[sl] = (u16)t;
                ((u16*)(ws + WS_OVL))[slot] = (u16)t;
                enc = (3u << 30) | (slot << 10) | slot;
            } else enc = ENC_RESCAN;
        }
        ws[f * NBX + t] = enc;
    }
    __syncthreads();

    // ---- pass 2: materialize neighbor lists into the global pool ----
    {
        u16* poolg = (u16*)(ws + WS_POOL);
        int cntc = (int)ofill; if (cntc > OVPF) cntc = OVPF;
        for (int sl = gw; sl < cntc; sl += 16) {
            int i = ovl_l[sl];
            int slot = f * OVPF + sl;
            int cai = classes[f * NBX + i];
            float4 ai = gbox[f * NBX + i];
            u32 mym = 0;
            if (ln < 32) {
                u32 m = ((cai & 1) ? clsb[0][ln] : ~clsb[0][ln])
                      & ((cai & 2) ? clsb[1][ln] : ~clsb[1][ln])
                      & ((cai & 4) ? clsb[2][ln] : ~clsb[2][ln]);
                while (m) {
                    int b = __ffs(m) - 1;
                    m &= m - 1;
                    if (iou_ge(ai, gbox[(f + 1) * NBX + ln * 32 + b])) mym |= 1u << b;
                }
            }
            int c = __popc(mym), inc = c;
            for (int off = 1; off < 64; off <<= 1) {
                int v = __shfl_up(inc, off);
                if (ln >= off) inc += v;
            }
            int deg = __shfl(inc, 63);
            int base = inc - c;
            if (deg <= PSTRIDE - 1) {
                if (ln == 0) poolg[slot * PSTRIDE] = (u16)deg;
                if (ln < 32) {
                    u32 m = mym; int idx = base;
                    while (m) {
                        int b = __ffs(m) - 1;
                        m &= m - 1;
                        poolg[slot * PSTRIDE + 1 + idx++] = (u16)(ln * 32 + b); // ascending j
                    }
                }
            } else if (ln == 0) poolg[slot * PSTRIDE] = (u16)DEG_RECOMP; // coop recompute
        }
        if (t == 0) ws[WS_OST2 + f] = (u32)cntc;
    }
}

// ========================= kernel 2: iterations =========================
// Rotated loop, 8 barriers/iter (was 10):
//   [fused: prev-suppression + DP f=6 (benign-race corrected reads)]
//   [f=5..0 steps; f=0 also folds the wave argmax reduce]
//   [wave 0: final reduce + traceback + stats + out-write + valid/done]
// Phase-B lanes merge their listed-row (v,rr) into the register argmax
// (associative max/min-index fold) -> no listed fix-up, no reduce barrier.
__global__ __launch_bounds__(512) void seqnms_iter(const float4* __restrict__ gbox,
                                                   const float* __restrict__ scores,
                                                   const int* __restrict__ classes,
                                                   float* __restrict__ out,
                                                   const u32* __restrict__ ws) {
    __shared__ float4 ms4[NTOT / 4];      // 32768
    __shared__ float4 seqbox[NFR];        // 128
    __shared__ float ssc[NTOT];           // 32768
    __shared__ u32 csr[NROW];             // 28672
    __shared__ u32 clsb7[7][3][32];       // 2688
    __shared__ u16 pool[OVTOT * PSTRIDE]; // 32768
    __shared__ u8 cls8[NTOT];             // 8192
    __shared__ u32 cnt_sh[8];
    __shared__ float redv[8];
    __shared__ int   redi[8];
    __shared__ int   sel_sh[NFR];
    __shared__ int   seqcls[NFR];
    __shared__ int   valid_sh, done_sh;
    __shared__ u16 ovl[OVTOT];
    __shared__ u8  ovact[OVTOT];

    float* ms = (float*)ms4;
    const int t = threadIdx.x, gw = t >> 6, ln = t & 63;
    const int sg = (gw << 3) + (ln >> 3), sl = ln & 7;   // subwave-8 id/lane

    // ---- reload adjacency state from workspace (coalesced) ----
    for (int idx = t; idx < NROW; idx += 512) csr[idx] = ws[idx];
    u32* p32 = (u32*)pool;
    for (int idx = t; idx < OVTOT * PSTRIDE / 2; idx += 512) p32[idx] = ws[WS_POOL + idx];
    if (t < 128) ((u32*)ovl)[t] = ws[WS_OVL + t];
    if (t < 7) cnt_sh[t] = ws[WS_OST2 + t];
    if (t < OVTOT) ovact[t] = 1;
    if (t == 0) { done_sh = 0; valid_sh = 0; }

    // ---- per-column registers + identity output + LDS copies ----
    float psc2[2][NFR]; u32 pclp[2] = {0u, 0u};
    #pragma unroll
    for (int f = 0; f < NFR; ++f) {
        #pragma unroll
        for (int c = 0; c < 2; ++c) {
            int i = t + (c << 9);
            float s = scores[f * NBX + i];
            int cl = classes[f * NBX + i];
            psc2[c][f] = s;
            pclp[c] |= (u32)cl << (3 * f);
            out[f * NBX + i] = s;           // identity part of reference output
            ssc[f * NBX + i] = s;
            cls8[f * NBX + i] = (u8)cl;
        }
    }
    // ---- class bitplanes (needed only for rare rescan paths) ----
    if (t < 224) {
        int fr = (t >> 5) + 1, w = t & 31;
        u32 p0 = 0, p1 = 0, p2 = 0;
        for (int b = 0; b < 32; ++b) {
            int c = classes[fr * NBX + w * 32 + b];
            p0 |= (u32)(c & 1) << b;
            p1 |= (u32)((c >> 1) & 1) << b;
            p2 |= (u32)((c >> 2) & 1) << b;
        }
        clsb7[fr - 1][0][w] = p0; clsb7[fr - 1][1][w] = p1; clsb7[fr - 1][2][w] = p2;
    }
    __syncthreads();

    // ---- iteration-invariant registers ----
    u32 pc2[2][7]; u32 lmask = 0;
    #pragma unroll
    for (int c = 0; c < 2; ++c) {
        #pragma unroll
        for (int f = 0; f < 7; ++f) {
            u32 p = csr[f * NBX + t + (c << 9)];
            pc2[c][f] = p;
            if ((p >> 30) == 3u && (p & 1023) == ((p >> 10) & 1023) && (p & 1023) != 1023)
                lmask |= 1u << (8 * c + f);     // listed: phase B owns the ms write
        }
    }
    int ose[7];                             // wave-uniform listed-range ends
    #pragma unroll
    for (int f = 0; f < 7; ++f) {
        int cv = (int)cnt_sh[f]; if (cv > OVPF) cv = OVPF;
        ose[f] = __builtin_amdgcn_readfirstlane(f * OVPF + cv);
    }
    u32 act = 0xFFFFu;                      // bit (8c+f) = active(f, col c)
    float ms7_0 = psc2[0][7], ms7_1 = psc2[1][7];
    ms[7 * NBX + t] = ms7_0;
    ms[7 * NBX + t + 512] = ms7_1;
    __syncthreads();

    // ---- 48 greedy extractions, 8 barriers each ----
    for (int it = 0; it < MAXS; ++it) {
        // ======== FUSED STEP: prev-iteration suppression + DP f=6 ========
        // (1) own-column suppression (valid-gated; no-op at it=0)
        if (valid_sh) {
            #pragma unroll
            for (int f = 0; f < NFR; ++f) {
                int sj = sel_sh[f];
                if (sj < 0) continue;                 // frame_in false
                int scl = seqcls[f];
                float4 sb = seqbox[f];
                #pragma unroll
                for (int c = 0; c < 2; ++c) {
                    int cl = (int)((pclp[c] >> (3 * f)) & 7u);
                    if (cl != scl) continue;
                    float4 b = gbox[f * NBX + t + (c << 9)];   // L1/L2-hot
                    if (iou_ge(sb, b)) act &= ~(1u << (8 * c + f));
                }
            }
            #pragma unroll
            for (int c = 0; c < 2; ++c) {
                #pragma unroll
                for (int f = 0; f < 7; ++f) if ((lmask >> (8 * c + f)) & 1)
                    ovact[pc2[c][f] & 1023] = (u8)((act >> (8 * c + f)) & 1); // unique owner
            }
            ms7_0 = ((act >> 7) & 1) ? psc2[0][7] : NEGV;
            ms7_1 = ((act >> 15) & 1) ? psc2[1][7] : NEGV;
            ms[7 * NBX + t] = ms7_0;      // benign race: write is identity unless
            ms[7 * NBX + t + 512] = ms7_1; // sup_now, and readers re-apply sup_now
        }
        float bv = ms7_0; int bi = 7 * NBX + t;
        { float v = ms7_1; int r = 7 * NBX + t + 512;
          if (v > bv || (v == bv && r < bi)) { bv = v; bi = r; } }

        // frame-7 corrected-read context (uniform flags; garbage-safe when off)
        const int sup7 = (valid_sh && sel_sh[7] >= 0) ? 1 : 0;
        const float4 sb7 = seqbox[7];
        const int scl7 = seqcls[7];
        const int sup6 = (valid_sh && sel_sh[6] >= 0) ? 1 : 0;
        const float4 sb6 = seqbox[6];
        const int scl6 = seqcls[6];
        {
            const float* msn = &ms[7 * NBX];
            auto rd7 = [&](int j) -> float {   // idempotent suppression-corrected read
                float v = msn[j];
                if (sup7 && (int)cls8[7 * NBX + j] == scl7 &&
                    iou_ge(sb7, gbox[7 * NBX + j])) v = NEGV;
                return v;
            };
            // (2) phase A f=6
            #pragma unroll
            for (int c = 0; c < 2; ++c) {
                const u32 p = pc2[c][6];
                const u32 cA = p >> 30, j0 = p & 1023, j1 = (p >> 10) & 1023;
                const bool ovf = (cA == 3u) && (j0 == j1);
                const int i = t + (c << 9);
                const int r = 6 * NBX + i;
                if (!ovf) {                          // inline rows (vast majority)
                    float v = NEGV;
                    if ((act >> (8 * c + 6)) & 1) {
                        float best = 0.0f;
                        if (cA >= 1) best = fmaxf(best, fmaxf(rd7((int)j0), 0.0f));
                        if (cA >= 2) best = fmaxf(best, fmaxf(rd7((int)j1), 0.0f));
                        if (cA >= 3) best = fmaxf(best, fmaxf(rd7((int)((p >> 20) & 1023)), 0.0f));
                        v = __fadd_rn(psc2[c][6], best);
                    }
                    ms[r] = v;
                    if (v > bv || (v == bv && r < bi)) { bv = v; bi = r; }
                } else if (j0 == 1023) {             // rescan (~never)
                    float v = NEGV;
                    if ((act >> (8 * c + 6)) & 1) {
                        float best = 0.0f;
                        int ca = (int)((pclp[c] >> 18) & 7u);
                        float4 a4 = gbox[r];
                        for (int w = 0; w < 32; ++w) {
                            u32 q0 = clsb7[6][0][w], q1 = clsb7[6][1][w], q2 = clsb7[6][2][w];
                            u32 m = ((ca & 1) ? q0 : ~q0) & ((ca & 2) ? q1 : ~q1) & ((ca & 4) ? q2 : ~q2);
                            while (m) {
                                int b = __ffs(m) - 1;
                                m &= m - 1;
                                int j = w * 32 + b;
                                float mv = rd7(j);
                                if (mv > 0.0f && iou_ge(a4, gbox[7 * NBX + j]))
                                    best = fmaxf(best, mv);
                            }
                        }
                        v = __fadd_rn(psc2[c][6], best);
                    }
                    ms[r] = v;
                    if (v > bv || (v == bv && r < bi)) { bv = v; bi = r; }
                }
            }
            // (3) phase B frame 6: corrected ovact + corrected reads; sl==0 merges
            {
                const int s1 = ose[6];
                for (int s = 6 * OVPF + sg; s < s1; s += 64) {
                    int i = ovl[s];
                    int rr = 6 * NBX + i;
                    bool actv = ovact[s] != 0;               // old or new: corrected below
                    if (actv && sup6) {
                        if ((int)cls8[rr] == scl6 && iou_ge(sb6, gbox[rr])) actv = false;
                    }
                    float best = 0.0f;
                    if (actv) {
                        int deg = (int)pool[s * PSTRIDE];
                        if (deg != (int)DEG_RECOMP) {
                            for (int q = sl; q < deg; q += 8)
                                best = fmaxf(best, fmaxf(rd7((int)pool[s * PSTRIDE + 1 + q]), 0.0f));
                        } else {                             // deg>63: recompute
                            int ca = (int)cls8[rr]; float4 a4 = gbox[rr];
                            for (int ww = 0; ww < 4; ++ww) {
                                int w = sl * 4 + ww;
                                u32 q0 = clsb7[6][0][w], q1 = clsb7[6][1][w], q2 = clsb7[6][2][w];
                                u32 m = ((ca & 1) ? q0 : ~q0) & ((ca & 2) ? q1 : ~q1) & ((ca & 4) ? q2 : ~q2);
                                while (m) {
                                    int b = __ffs(m) - 1;
                                    m &= m - 1;
                                    int j = w * 32 + b;
                                    if (iou_ge(a4, gbox[7 * NBX + j]))
                                        best = fmaxf(best, fmaxf(rd7(j), 0.0f));
                                }
                            }
                        }
                        best = fmaxf(best, __shfl_xor(best, 1));
                        best = fmaxf(best, __shfl_xor(best, 2));
                        best = fmaxf(best, __shfl_xor(best, 4));
                    }
                    if (sl == 0) {
                        float v = actv ? __fadd_rn(ssc[rr], best) : NEGV;
                        ms[rr] = v;
                        if (v > bv || (v == bv && rr < bi)) { bv = v; bi = rr; }
                    }
                }
            }
        }
        __syncthreads();                                  // barrier 1

        // ======== steps f=5..0 (f=0 folds the wave argmax reduce) ========
        #pragma unroll
        for (int f = 5; f >= 0; --f) {
            const float* msn = &ms[(f + 1) * NBX];
            #pragma unroll
            for (int c = 0; c < 2; ++c) {
                const u32 p = pc2[c][f];
                const u32 cA = p >> 30, j0 = p & 1023, j1 = (p >> 10) & 1023;
                const bool ovf = (cA == 3u) && (j0 == j1);
                const int i = t + (c << 9);
                const int r = f * NBX + i;
                if (!ovf) {                          // inline rows (vast majority)
                    float v = NEGV;
                    if ((act >> (8 * c + f)) & 1) {
                        float best = 0.0f;           // == ref max(where(eff, ms_next, 0))
                        if (cA >= 1) best = fmaxf(best, fmaxf(msn[j0], 0.0f));
                        if (cA >= 2) best = fmaxf(best, fmaxf(msn[j1], 0.0f));
                        if (cA >= 3) best = fmaxf(best, fmaxf(msn[(p >> 20) & 1023], 0.0f));
                        v = __fadd_rn(psc2[c][f], best);
                    }
                    ms[r] = v;
                    if (v > bv || (v == bv && r < bi)) { bv = v; bi = r; }
                } else if (j0 == 1023) {             // rescan (~never)
                    float v = NEGV;
                    if ((act >> (8 * c + f)) & 1) {
                        float best = 0.0f;
                        int ca = (int)((pclp[c] >> (3 * f)) & 7u);
                        float4 a4 = gbox[r];
                        for (int w = 0; w < 32; ++w) {
                            u32 q0 = clsb7[f][0][w], q1 = clsb7[f][1][w], q2 = clsb7[f][2][w];
                            u32 m = ((ca & 1) ? q0 : ~q0) & ((ca & 2) ? q1 : ~q1) & ((ca & 4) ? q2 : ~q2);
                            while (m) {
                                int b = __ffs(m) - 1;
                                m &= m - 1;
                                int j = w * 32 + b;
                                float mv = msn[j];
                                if (mv > 0.0f && iou_ge(a4, gbox[(f + 1) * NBX + j]))
                                    best = fmaxf(best, mv);
                            }
                        }
                        v = __fadd_rn(psc2[c][f], best);
                    }
                    ms[r] = v;
                    if (v > bv || (v == bv && r < bi)) { bv = v; bi = r; }
                }
            }
            // phase B frame f (fenced state); sl==0 merges (v, rr)
            {
                const int s1 = ose[f];
                for (int s = f * OVPF + sg; s < s1; s += 64) {
                    int i = ovl[s];
                    int rr = f * NBX + i;
                    bool actv = ovact[s] != 0;       // subgroup-uniform
                    float best = 0.0f;
                    if (actv) {
                        int deg = (int)pool[s * PSTRIDE];
                        if (deg != (int)DEG_RECOMP) {
                            for (int q = sl; q < deg; q += 8)
                                best = fmaxf(best, fmaxf(msn[pool[s * PSTRIDE + 1 + q]], 0.0f));
                        } else {                     // deg>63: recompute, 4 words/lane
                            int ca = (int)cls8[rr]; float4 a4 = gbox[rr];
                            for (int ww = 0; ww < 4; ++ww) {
                                int w = sl * 4 + ww;
                                u32 q0 = clsb7[f][0][w], q1 = clsb7[f][1][w], q2 = clsb7[f][2][w];
                                u32 m = ((ca & 1) ? q0 : ~q0) & ((ca & 2) ? q1 : ~q1) & ((ca & 4) ? q2 : ~q2);
                                while (m) {
                                    int b = __ffs(m) - 1;
                                    m &= m - 1;
                                    int j = w * 32 + b;
                                    if (iou_ge(a4, gbox[(f + 1) * NBX + j]))
                                        best = fmaxf(best, fmaxf(msn[j], 0.0f));
                                }
                            }
                        }
                        best = fmaxf(best, __shfl_xor(best, 1));
                        best = fmaxf(best, __shfl_xor(best, 2));
                        best = fmaxf(best, __shfl_xor(best, 4));
                    }
                    if (sl == 0) {
                        float v = actv ? __fadd_rn(ssc[rr], best) : NEGV;
                        ms[rr] = v;
                        if (v > bv || (v == bv && rr < bi)) { bv = v; bi = rr; }
                    }
                }
            }
            if (f == 0) {   // fold wave argmax reduce before the trailing barrier
                #pragma unroll
                for (int off = 32; off > 0; off >>= 1) {
                    float ov = __shfl_down(bv, off); int oi = __shfl_down(bi, off);
                    if (ov > bv || (ov == bv && oi < bi)) { bv = ov; bi = oi; }
                }
                if (ln == 0) { redv[gw] = bv; redi[gw] = bi; }
            }
            __syncthreads();                          // barriers 2..7
        }

        // ======== wave 0: final reduce + traceback + stats + publish ========
        if (t < 64) {
            float v = (ln < 8) ? redv[ln] : -3.0e38f;
            int i0 = (ln < 8) ? redi[ln] : 0x7fffffff;
            #pragma unroll
            for (int off = 4; off > 0; off >>= 1) {
                float ov = __shfl_down(v, off); int oi = __shfl_down(i0, off);
                if (ov > v || (ov == v && oi < i0)) { v = ov; i0 = oi; }
            }
            v = __shfl(v, 0); i0 = __shfl(i0, 0);
            const float bestval = v;
            const int fstar = i0 >> 10, istar = i0 & (NBX - 1);
            if (ln < NFR) sel_sh[ln] = -1;
            int cur = istar;
            for (int f = fstar; f < NFR; ++f) {       // all breaks wave-uniform
                if (ln == 0) sel_sh[f] = cur;
                if (f == 7) break;                    // adj_pad[7] all-zero
                u32 p = csr[f * NBX + cur];
                u32 c = p >> 30, j0 = p & 1023, j1 = (p >> 10) & 1023;
                const float* msn = &ms[(f + 1) * NBX];
                if (!((c == 3u) && (j0 == j1))) {     // inline: all-lane redundant
                    float tb = -3.0e38f; int tj = -1; // ascending j + strict >
                    if (c >= 1) { float m = msn[j0]; if (m != NEGV) { tb = m; tj = (int)j0; } }
                    if (c >= 2) { float m = msn[j1]; if (m != NEGV && m > tb) { tb = m; tj = (int)j1; } }
                    if (c >= 3) { int j2 = (p >> 20) & 1023; float m = msn[j2];
                                  if (m != NEGV && m > tb) { tb = m; tj = j2; } }
                    if (tj < 0) break;                // !has_link
                    cur = tj;
                } else {                              // listed / rescan: cooperative
                    float tv = -3.0e38f; int tj = 0x7fffffff;
                    bool recomp = true;
                    if (j0 != 1023) {
                        int s = (int)j0;
                        int deg = (int)pool[s * PSTRIDE];
                        if (deg != (int)DEG_RECOMP) {
                            recomp = false;
                            for (int q = ln; q < deg; q += 64) {
                                int j = (int)pool[s * PSTRIDE + 1 + q];
                                float m = msn[j];
                                if (m != NEGV && (m > tv || (m == tv && j < tj))) { tv = m; tj = j; }
                            }
                        }
                    }
                    if (recomp) {
                        int ca = (int)cls8[f * NBX + cur]; float4 a4 = gbox[f * NBX + cur];
                        if (ln < 32) {
                            u32 q0 = clsb7[f][0][ln], q1 = clsb7[f][1][ln], q2 = clsb7[f][2][ln];
                            u32 m = ((ca & 1) ? q0 : ~q0) & ((ca & 2) ? q1 : ~q1) & ((ca & 4) ? q2 : ~q2);
                            while (m) {
                                int b = __ffs(m) - 1;
                                m &= m - 1;
                                int j = ln * 32 + b;
                                float mv = msn[j];
                                if (mv != NEGV && iou_ge(a4, gbox[(f + 1) * NBX + j])) {
                                    if (mv > tv || (mv == tv && j < tj)) { tv = mv; tj = j; }
                                }
                            }
                        }
                    }
                    #pragma unroll
                    for (int off = 32; off > 0; off >>= 1) {
                        float ov = __shfl_down(tv, off); int oj = __shfl_down(tj, off);
                        if (ov > tv || (ov == tv && oj < tj)) { tv = ov; tj = oj; }
                    }
                    tv = __shfl(tv, 0); tj = __shfl(tj, 0);
                    if (tv < -1.0e37f) break;         // !has_link
                    cur = tj;
                }
            }
            // stats (avg is output-only; len/bestval steering is exact)
            float sv = 0.0f; int cc = 0;
            if (ln < NFR) {
                int sj = sel_sh[ln];
                if (sj >= 0) {
                    sv = ssc[(ln << 10) + sj]; cc = 1;
                    seqbox[ln] = gbox[(ln << 10) + sj];
                    seqcls[ln] = (int)cls8[(ln << 10) + sj];
                }
            }
            #pragma unroll
            for (int off = 4; off > 0; off >>= 1) {
                sv = __fadd_rn(sv, __shfl_down(sv, off));
                cc += __shfl_down(cc, off);
            }
            sv = __shfl(sv, 0); cc = __shfl(cc, 0);
            int dprev = done_sh;                      // read-before-write, same wave
            float avg = __fdiv_rn(sv, (float)cc);     // cc >= 1 always
            bool ok = (cc > 1) && (bestval > 0.0f);
            int validf = (ok && !dprev) ? 1 : 0;
            if (ln == 0) { valid_sh = validf; if (!ok) done_sh = 1; }
            if (validf && ln < NFR) {
                int sj = sel_sh[ln];
                if (sj >= 0) out[ln * NBX + sj] = avg;
            }
        }
        __syncthreads();                              // barrier 8
        if (done_sh) break;   // uniform; remaining reference iterations are no-ops
    }
}

// ================== fallback: verified round-2 monolith ==================
#define OVTOTF 256
#define ENC_PENDING ((3u << 30) | (1022u << 10) | 1022u)
__global__ __launch_bounds__(1024) void seqnms_full(const float4* __restrict__ gbox,
                                                    const float* __restrict__ scores,
                                                    const int* __restrict__ classes,
                                                    float* __restrict__ out) {
    __shared__ float4 ms4[NTOT / 4];
    __shared__ float4 seqbox[NFR];
    __shared__ float ssc[NTOT];
    __shared__ u32 csr[NROW];
    __shared__ u32 clsb7[7][3][32];
    __shared__ u16 pool[OVTOTF * PSTRIDE];
    __shared__ u8 cls8[NTOT];
    __shared__ u32 ostart[8];
    __shared__ u32 ofill[7];
    __shared__ u32 ocnt[7];
    __shared__ float redv[16];
    __shared__ int   redi[16];
    __shared__ int   sel_sh[NFR];
    __shared__ int   seqcls[NFR];
    __shared__ float avg_sh;
    __shared__ int   valid_sh, done_sh;
    __shared__ u16 ovl[OVTOTF];
    __shared__ u8  ovact[OVTOTF];

    float* ms = (float*)ms4;
    const int t = threadIdx.x, gw = t >> 6, ln = t & 63;

    float psc[NFR]; int pcl[NFR]; float4 pbx[NFR];
    #pragma unroll
    for (int f = 0; f < NFR; ++f) {
        psc[f] = scores[f * NBX + t];
        pcl[f] = classes[f * NBX + t];
        pbx[f] = gbox[f * NBX + t];
        out[f * NBX + t] = psc[f];
        ssc[f * NBX + t] = psc[f];
        cls8[f * NBX + t] = (u8)pcl[f];
    }
    if (t < 7) { ocnt[t] = 0; ofill[t] = 0; }
    if (t < OVTOTF) ovact[t] = 1;
    if (t == 0) done_sh = 0;

    if (t < 224) {
        int fr = (t >> 5) + 1, w = t & 31;
        u32 p0 = 0, p1 = 0, p2 = 0;
        for (int b = 0; b < 32; ++b) {
            int c = classes[fr * NBX + w * 32 + b];
            p0 |= (u32)(c & 1) << b;
            p1 |= (u32)((c >> 1) & 1) << b;
            p2 |= (u32)((c >> 2) & 1) << b;
        }
        clsb7[fr - 1][0][w] = p0; clsb7[fr - 1][1][w] = p1; clsb7[fr - 1][2][w] = p2;
    }
    __syncthreads();

    for (int f = 0; f < 7; ++f) {
        ms4[t] = pbx[f + 1];
        __syncthreads();
        const int r = f * NBX + t;
        const int ca = pcl[f];
        const float4 a4 = pbx[f];
        u32 cnt = 0, j0 = 0, j1 = 0, j2 = 0;
        for (int w = 0; w < 32; ++w) {
            u32 q0 = clsb7[f][0][w], q1 = clsb7[f][1][w], q2 = clsb7[f][2][w];
            u32 m = ((ca & 1) ? q0 : ~q0) & ((ca & 2) ? q1 : ~q1) & ((ca & 4) ? q2 : ~q2);
            while (m) {
                int b = __ffs(m) - 1;
                m &= m - 1;
                int j = w * 32 + b;
                if (iou_ge(a4, ms4[j])) {
                    if (cnt == 0) j0 = j; else if (cnt == 1) j1 = j; else if (cnt == 2) j2 = j;
                    ++cnt;
                }
            }
        }
        if (cnt <= 3) csr[r] = (cnt << 30) | (j2 << 20) | (j1 << 10) | j0;
        else { atomicAdd(&ocnt[f], 1u); csr[r] = ENC_PENDING; }
        __syncthreads();
    }
    if (t == 0) {
        u32 s = 0;
        for (int f = 0; f < 7; ++f) { ostart[f] = s; s += ocnt[f]; }
        ostart[7] = s;
    }
    __syncthreads();
    for (int f = 0; f < 7; ++f) {
        int r = f * NBX + t;
        if (csr[r] == ENC_PENDING) {
            u32 slot = ostart[f] + atomicAdd(&ofill[f], 1u);
            if (slot < OVTOTF) { ovl[slot] = (u16)t; csr[r] = (3u << 30) | (slot << 10) | slot; }
            else csr[r] = ENC_RESCAN;
        }
    }
    __syncthreads();
    {
        int total = (int)ostart[7]; if (total > OVTOTF) total = OVTOTF;
        for (int s = gw; s < total; s += 16) {
            int f = 0;
            while (s >= (int)ostart[f + 1]) ++f;
            int i = ovl[s];
            int ca = (int)cls8[f * NBX + i];
            float4 a4 = gbox[f * NBX + i];
            u32 mym = 0;
            if (ln < 32) {
                u32 q0 = clsb7[f][0][ln], q1 = clsb7[f][1][ln], q2 = clsb7[f][2][ln];
                u32 m = ((ca & 1) ? q0 : ~q0) & ((ca & 2) ? q1 : ~q1) & ((ca & 4) ? q2 : ~q2);
                while (m) {
                    int b = __ffs(m) - 1;
                    m &= m - 1;
                    if (iou_ge(a4, gbox[(f + 1) * NBX + ln * 32 + b])) mym |= 1u << b;
                }
            }
            int c = __popc(mym), inc = c;
            for (int off = 1; off < 64; off <<= 1) {
                int v = __shfl_up(inc, off);
                if (ln >= off) inc += v;
            }
            int deg = __shfl(inc, 63);
            int base = inc - c;
            if (deg <= PSTRIDE - 1) {
                if (ln == 0) pool[s * PSTRIDE] = (u16)deg;
                if (ln < 32) {
                    u32 m = mym; int idx = base;
                    while (m) {
                        int b = __ffs(m) - 1;
                        m &= m - 1;
                        pool[s * PSTRIDE + 1 + idx++] = (u16)(ln * 32 + b);
                    }
                }
            } else if (ln == 0) pool[s * PSTRIDE] = (u16)DEG_RECOMP;
        }
    }
    __syncthreads();

    u32 pc[7]; u32 lmask = 0;
    #pragma unroll
    for (int f = 0; f < 7; ++f) {
        u32 p = csr[f * NBX + t];
        pc[f] = p;
        if ((p >> 30) == 3u && (p & 1023) == ((p >> 10) & 1023) && (p & 1023) != 1023)
            lmask |= 1u << f;
    }
    int os[8];
    #pragma unroll
    for (int f = 0; f < 8; ++f) {
        int v = (int)ostart[f]; if (v > OVTOTF) v = OVTOTF;
        os[f] = __builtin_amdgcn_readfirstlane(v);
    }
    u32 act = 0xFF;
    float ms7 = psc[7];
    ms[7 * NBX + t] = ms7;
    __syncthreads();

    for (int it = 0; it < MAXS; ++it) {
        float bv = ms7; int bi = 7 * NBX + t;
        #pragma unroll
        for (int f = 6; f >= 0; --f) {
            const float* msn = &ms[(f + 1) * NBX];
            const u32 p = pc[f];
            const u32 c = p >> 30, j0 = p & 1023, j1 = (p >> 10) & 1023;
            const bool ovf = (c == 3u) && (j0 == j1);
            const int r = f * NBX + t;
            if (!ovf) {
                float v = NEGV;
                if ((act >> f) & 1) {
                    float best = 0.0f;
                    if (c >= 1) best = fmaxf(best, fmaxf(msn[j0], 0.0f));
                    if (c >= 2) best = fmaxf(best, fmaxf(msn[j1], 0.0f));
                    if (c >= 3) best = fmaxf(best, fmaxf(msn[(p >> 20) & 1023], 0.0f));
                    v = __fadd_rn(psc[f], best);
                }
                ms[r] = v;
                if (v > bv || (v == bv && r < bi)) { bv = v; bi = r; }
            } else if (j0 == 1023) {
                float v = NEGV;
                if ((act >> f) & 1) {
                    float best = 0.0f;
                    int ca = pcl[f]; float4 a4 = pbx[f];
                    for (int w = 0; w < 32; ++w) {
                        u32 q0 = clsb7[f][0][w], q1 = clsb7[f][1][w], q2 = clsb7[f][2][w];
                        u32 m = ((ca & 1) ? q0 : ~q0) & ((ca & 2) ? q1 : ~q1) & ((ca & 4) ? q2 : ~q2);
                        while (m) {
                            int b = __ffs(m) - 1;
                            m &= m - 1;
                            int j = w * 32 + b;
                            float mv = msn[j];
                            if (mv > 0.0f && iou_ge(a4, gbox[(f + 1) * NBX + j]))
                                best = fmaxf(best, mv);
                        }
                    }
                    v = __fadd_rn(psc[f], best);
                }
                ms[r] = v;
                if (v > bv || (v == bv && r < bi)) { bv = v; bi = r; }
            }
            {
                const int s1 = os[f + 1];
                for (int s = os[f] + gw; s < s1; s += 16) {
                    int i = ovl[s];
                    int rr = f * NBX + i;
                    bool actv = ovact[s] != 0;
                    float best = 0.0f;
                    if (actv) {
                        int deg = (int)pool[s * PSTRIDE];
                        if (deg != (int)DEG_RECOMP) {
                            for (int q = ln; q < deg; q += 64)
                                best = fmaxf(best, fmaxf(msn[pool[s * PSTRIDE + 1 + q]], 0.0f));
                        } else {
                            int ca = (int)cls8[rr]; float4 a4 = gbox[rr];
                            if (ln < 32) {
                                u32 q0 = clsb7[f][0][ln], q1 = clsb7[f][1][ln], q2 = clsb7[f][2][ln];
                                u32 m = ((ca & 1) ? q0 : ~q0) & ((ca & 2) ? q1 : ~q1) & ((ca & 4) ? q2 : ~q2);
                                while (m) {
                                    int b = __ffs(m) - 1;
                                    m &= m - 1;
                                    int j = ln * 32 + b;
                                    if (iou_ge(a4, gbox[(f + 1) * NBX + j]))
                                        best = fmaxf(best, fmaxf(msn[j], 0.0f));
                                }
                            }
                        }
                        #pragma unroll
                        for (int off = 32; off > 0; off >>= 1)
                            best = fmaxf(best, __shfl_down(best, off));
                    }
                    if (ln == 0) ms[rr] = actv ? __fadd_rn(ssc[rr], best) : NEGV;
                }
            }
            __syncthreads();
        }

        #pragma unroll
        for (int f = 0; f < 7; ++f) if ((lmask >> f) & 1) {
            int r = f * NBX + t; float v = ms[r];
            if (v > bv || (v == bv && r < bi)) { bv = v; bi = r; }
        }
        #pragma unroll
        for (int off = 32; off > 0; off >>= 1) {
            float ov = __shfl_down(bv, off); int oi = __shfl_down(bi, off);
            if (ov > bv || (ov == bv && oi < bi)) { bv = ov; bi = oi; }
        }
        if (ln == 0) { redv[gw] = bv; redi[gw] = bi; }
        __syncthreads();

        if (t < 64) {
            float v = (ln < 16) ? redv[ln] : -3.0e38f;
            int i0 = (ln < 16) ? redi[ln] : 0x7fffffff;
            #pragma unroll
            for (int off = 8; off > 0; off >>= 1) {
                float ov = __shfl_down(v, off); int oi = __shfl_down(i0, off);
                if (ov > v || (ov == v && oi < i0)) { v = ov; i0 = oi; }
            }
            v = __shfl(v, 0); i0 = __shfl(i0, 0);
            const float bestval = v;
            const int fstar = i0 >> 10, istar = i0 & (NBX - 1);
            if (ln < NFR) sel_sh[ln] = -1;
            int cur = istar;
            for (int f = fstar; f < NFR; ++f) {
                if (ln == 0) sel_sh[f] = cur;
                if (f == 7) break;
                u32 p = csr[f * NBX + cur];
                u32 c = p >> 30, j0 = p & 1023, j1 = (p >> 10) & 1023;
                const float* msn = &ms[(f + 1) * NBX];
                if (!((c == 3u) && (j0 == j1))) {
                    float tb = -3.0e38f; int tj = -1;
                    if (c >= 1) { float m = msn[j0]; if (m != NEGV) { tb = m; tj = (int)j0; } }
                    if (c >= 2) { float m = msn[j1]; if (m != NEGV && m > tb) { tb = m; tj = (int)j1; } }
                    if (c >= 3) { int j2 = (p >> 20) & 1023; float m = msn[j2];
                                  if (m != NEGV && m > tb) { tb = m; tj = j2; } }
                    if (tj < 0) break;
                    cur = tj;
                } else {
                    float tv = -3.0e38f; int tj = 0x7fffffff;
                    bool recomp = true;
                    if (j0 != 1023) {
                        int s = (int)j0;
                        int deg = (int)pool[s * PSTRIDE];
                        if (deg != (int)DEG_RECOMP) {
                            recomp = false;
                            for (int q = ln; q < deg; q += 64) {
                                int j = (int)pool[s * PSTRIDE + 1 + q];
                                float m = msn[j];
                                if (m != NEGV && (m > tv || (m == tv && j < tj))) { tv = m; tj = j; }
                            }
                        }
                    }
                    if (recomp) {
                        int ca = (int)cls8[f * NBX + cur]; float4 a4 = gbox[f * NBX + cur];
                        if (ln < 32) {
                            u32 q0 = clsb7[f][0][ln], q1 = clsb7[f][1][ln], q2 = clsb7[f][2][ln];
                            u32 m = ((ca & 1) ? q0 : ~q0) & ((ca & 2) ? q1 : ~q1) & ((ca & 4) ? q2 : ~q2);
                            while (m) {
                                int b = __ffs(m) - 1;
                                m &= m - 1;
                                int j = ln * 32 + b;
                                float mv = msn[j];
                                if (mv != NEGV && iou_ge(a4, gbox[(f + 1) * NBX + j])) {
                                    if (mv > tv || (mv == tv && j < tj)) { tv = mv; tj = j; }
                                }
                            }
                        }
                    }
                    #pragma unroll
                    for (int off = 32; off > 0; off >>= 1) {
                        float ov = __shfl_down(tv, off); int oj = __shfl_down(tj, off);
                        if (ov > tv || (ov == tv && oj < tj)) { tv = ov; tj = oj; }
                    }
                    tv = __shfl(tv, 0); tj = __shfl(tj, 0);
                    if (tv < -1.0e37f) break;
                    cur = tj;
                }
            }
            float sv = 0.0f; int cc = 0;
            if (ln < NFR) {
                int sj = sel_sh[ln];
                if (sj >= 0) {
                    sv = ssc[ln * NBX + sj]; cc = 1;
                    seqbox[ln] = gbox[ln * NBX + sj];
                    seqcls[ln] = (int)cls8[ln * NBX + sj];
                }
            }
            #pragma unroll
            for (int off = 4; off > 0; off >>= 1) {
                sv = __fadd_rn(sv, __shfl_down(sv, off));
                cc += __shfl_down(cc, off);
            }
            if (ln == 0) {
                avg_sh = __fdiv_rn(sv, (float)cc);
                bool ok = (cc > 1) && (bestval > 0.0f);
                valid_sh = (ok && !done_sh) ? 1 : 0;
                if (!ok) done_sh = 1;
            }
        }
        __syncthreads();

        if (valid_sh) {
            #pragma unroll
            for (int f = 0; f < NFR; ++f) {
                int sj = sel_sh[f];
                if (sj < 0) continue;
                if (pcl[f] != seqcls[f]) continue;
                if (iou_ge(seqbox[f], pbx[f])) act &= ~(1u << f);
            }
            #pragma unroll
            for (int f = 0; f < 7; ++f) if ((lmask >> f) & 1)
                ovact[pc[f] & 1023] = (u8)((act >> f) & 1);
            ms7 = (act & 0x80) ? psc[7] : NEGV;
            ms[7 * NBX + t] = ms7;
            if (t < NFR) {
                int sj = sel_sh[t];
                if (sj >= 0) out[t * NBX + sj] = avg_sh;
            }
        }
        __syncthreads();
        if (done_sh) break;
    }
}

extern "C" void kernel_launch(void* const* d_in, const int* in_sizes, int n_in,
                              void* d_out, int out_size, void* d_ws, size_t ws_size,
                              hipStream_t stream) {
    const float4* boxes = (const float4*)d_in[0];     // (8,1024,4) float32
    const float* scores = (const float*)d_in[1];      // (8,1024) float32
    const int* classes = (const int*)d_in[2];         // (8,1024) int32
    float* out = (float*)d_out;                       // (8,1024) float32
    const int use_split =
        (d_ws != nullptr && ws_size >= (size_t)(WS_WORDS * 4)) ? 1 : 0;
    if (use_split) {
        seqnms_setup<<<7, 1024, 0, stream>>>(boxes, classes, (u32*)d_ws);
        seqnms_iter<<<1, 512, 0, stream>>>(boxes, scores, classes, out, (const u32*)d_ws);
    } else {
        seqnms_full<<<1, 1024, 0, stream>>>(boxes, scores, classes, out);
    }
}

// Round 9
// 623.303 us; speedup vs baseline: 1.0808x; 1.0808x over previous
//
#include <hip/hip_runtime.h>

typedef unsigned int u32;
typedef unsigned short u16;
typedef unsigned char u8;

#define NFR 8
#define NBX 1024
#define NTOT 8192     // 8*1024
#define NROW 7168     // 7*1024 adjacency rows
#define MAXS 48
#define NEGV -1000000000.0f
#define OVTOT 256     // total slot array size in iter kernel
#define OVPF 36       // per-frame slot budget (7*36 = 252 <= 256)
#define PSTRIDE 64    // pool u16 per listed row: [deg, j0..j_{deg-1}], deg<=63
#define DEG_RECOMP 0xFFFF
#define ENC_RESCAN  ((3u << 30) | (1023u << 10) | 1023u)

// d_ws layout in u32 units: csr[7168] | pool(8192) | ovl(128) | cnt(8)
#define WS_POOL 7168
#define WS_OVL  (7168 + 8192)
#define WS_OST2 (WS_OVL + 128)
#define WS_WORDS (WS_OST2 + 8)      // 15496 u32 = 61984 bytes

// Exact predicate IoU(a,b) >= 0.2 in f32, _rn ops in the reference's
// association order (area_a from 'a' first). Early exits are exact:
// wx<=0 or wy<=0  =>  inter==0 in the reference  =>  iou==0 < 0.2.
__device__ __forceinline__ bool iou_ge(const float4 a, const float4 b) {
    float wx = __fsub_rn(fminf(a.z, b.z), fmaxf(a.x, b.x));
    if (!(wx > 0.0f)) return false;
    float wy = __fsub_rn(fminf(a.w, b.w), fmaxf(a.y, b.y));
    if (!(wy > 0.0f)) return false;
    float inter = __fmul_rn(wx, wy);
    float aa = __fmul_rn(__fsub_rn(a.z, a.x), __fsub_rn(a.w, a.y));
    float ab = __fmul_rn(__fsub_rn(b.z, b.x), __fsub_rn(b.w, b.y));
    float den = __fadd_rn(__fsub_rn(__fadd_rn(aa, ab), inter), 1e-8f);
    return __fdiv_rn(inter, den) >= 0.2f;
}

// x-bin for interval pruning: 32 bins of width 3.5 over [-6, 106].
__device__ __forceinline__ int xbin(float x) {
    int b = (int)floorf(__fmul_rn(__fadd_rn(x, 6.0f), 0.2857142857f)); // 1/3.5
    return b < 0 ? 0 : (b > 31 ? 31 : b);
}

// csr row encoding (u32): top 2 bits = cnt.
//   inline (cnt<=3): (cnt<<30)|(j2<<20)|(j1<<10)|j0, ascending -> j0!=j1 if cnt==3
//   listed overflow: (3<<30)|(slot<<10)|slot, slot = f*OVPF + local < 252
//   rescan fallback: slot field == 1023 (per-frame budget exhausted; ~never)

// ============================ kernel 1: setup ============================
// (verified round-7 version, unchanged) 7 independent blocks, one per
// frame-pair, each writing its disjoint ws region.
__global__ __launch_bounds__(1024) void seqnms_setup(const float4* __restrict__ gbox,
                                                     const int* __restrict__ classes,
                                                     u32* __restrict__ ws) {
    __shared__ u32 clsb[3][32];     // class bitplanes, frame f+1 (pass 2 use)
    __shared__ u32 cmask[8][32];    // per-class word masks, frame f+1
    __shared__ u32 xbm[32][32];     // [word][bin] x-interval mask, frame f+1
    __shared__ u16 ovl_l[OVPF];
    __shared__ u32 ofill;

    const int f = blockIdx.x;       // 0..6
    const int t = threadIdx.x, gw = t >> 6, ln = t & 63;

    if (t < 32 * 32) ((u32*)xbm)[t] = 0;
    if (t < 256) ((u32*)cmask)[t] = 0;
    if (t < 96) ((u32*)clsb)[t] = 0;
    if (t == 0) ofill = 0;

    const float4 a4 = gbox[f * NBX + t];          // own row's box (frame f)
    const int ca = classes[f * NBX + t];
    const float4 nb4 = gbox[(f + 1) * NBX + t];   // own box in frame f+1
    const int ncl = classes[(f + 1) * NBX + t];
    __syncthreads();

    // ---- fill masks: one atomic pass over frame f+1 ----
    {
        const u32 bit = 1u << (t & 31); const int wrd = t >> 5;
        int b0 = xbin(nb4.x), b1 = xbin(nb4.z);
        for (int b = b0; b <= b1; ++b) atomicOr(&xbm[wrd][b], bit);
        atomicOr(&cmask[ncl][wrd], bit);
        if (ncl & 1) atomicOr(&clsb[0][wrd], bit);
        if (ncl & 2) atomicOr(&clsb[1][wrd], bit);
        if (ncl & 4) atomicOr(&clsb[2][wrd], bit);
    }
    __syncthreads();

    // ---- row scan (ascending j; exact predicate after superset filter) ----
    {
        const int rb0 = xbin(a4.x), rb1 = xbin(a4.z);
        const float4* nb = gbox + (f + 1) * NBX;
        u32 cnt = 0, j0 = 0, j1 = 0, j2 = 0;
        for (int w = 0; w < 32; ++w) {
            u32 mx = xbm[w][rb0];
            for (int b = rb0 + 1; b <= rb1; ++b) mx |= xbm[w][b];
            if (!mx) continue;
            u32 m = mx & cmask[ca][w];
            while (m) {
                int b = __ffs(m) - 1;
                m &= m - 1;
                int j = w * 32 + b;
                if (iou_ge(a4, nb[j])) {
                    if (cnt == 0) j0 = j; else if (cnt == 1) j1 = j; else if (cnt == 2) j2 = j;
                    ++cnt;
                }
            }
        }
        u32 enc;
        if (cnt <= 3) enc = (cnt << 30) | (j2 << 20) | (j1 << 10) | j0;
        else {
            u32 sl = atomicAdd(&ofill, 1u);
            if (sl < OVPF) {
                u32 slot = (u32)(f * OVPF) + sl;
                ovl_l[sl] = (u16)t;
                ((u16*)(ws + WS_OVL))[slot] = (u16)t;
                enc = (3u << 30) | (slot << 10) | slot;
            } else enc = ENC_RESCAN;
        }
        ws[f * NBX + t] = enc;
    }
    __syncthreads();

    // ---- pass 2: materialize neighbor lists into the global pool ----
    {
        u16* poolg = (u16*)(ws + WS_POOL);
        int cntc = (int)ofill; if (cntc > OVPF) cntc = OVPF;
        for (int sl = gw; sl < cntc; sl += 16) {
            int i = ovl_l[sl];
            int slot = f * OVPF + sl;
            int cai = classes[f * NBX + i];
            float4 ai = gbox[f * NBX + i];
            u32 mym = 0;
            if (ln < 32) {
                u32 m = ((cai & 1) ? clsb[0][ln] : ~clsb[0][ln])
                      & ((cai & 2) ? clsb[1][ln] : ~clsb[1][ln])
                      & ((cai & 4) ? clsb[2][ln] : ~clsb[2][ln]);
                while (m) {
                    int b = __ffs(m) - 1;
                    m &= m - 1;
                    if (iou_ge(ai, gbox[(f + 1) * NBX + ln * 32 + b])) mym |= 1u << b;
                }
            }
            int c = __popc(mym), inc = c;
            for (int off = 1; off < 64; off <<= 1) {
                int v = __shfl_up(inc, off);
                if (ln >= off) inc += v;
            }
            int deg = __shfl(inc, 63);
            int base = inc - c;
            if (deg <= PSTRIDE - 1) {
                if (ln == 0) poolg[slot * PSTRIDE] = (u16)deg;
                if (ln < 32) {
                    u32 m = mym; int idx = base;
                    while (m) {
                        int b = __ffs(m) - 1;
                        m &= m - 1;
                        poolg[slot * PSTRIDE + 1 + idx++] = (u16)(ln * 32 + b); // ascending j
                    }
                }
            } else if (ln == 0) poolg[slot * PSTRIDE] = (u16)DEG_RECOMP; // coop recompute
        }
        if (t == 0) ws[WS_OST2 + f] = (u32)cntc;
    }
}

// ========================= kernel 2: iterations =========================
// Round-7 verified structure (552 us) with the SAFE subset of round 8:
//  (a) phase-B sl==0 lane merges its listed-row (v,rr) into the register
//      argmax (associative max/min-index fold) -> no listed fix-up pass;
//  (b) wave argmax reduce folded before f=0's trailing barrier -> the
//      dedicated reduce barrier is gone (9 barriers/iter, was 10);
//  (c) out-write in wave 0 (broadcast sv/cc, bitwise-identical value).
// NO benign-race suppression fusion, NO corrected reads (round-8 poison).
__global__ __launch_bounds__(512) void seqnms_iter(const float4* __restrict__ gbox,
                                                   const float* __restrict__ scores,
                                                   const int* __restrict__ classes,
                                                   float* __restrict__ out,
                                                   const u32* __restrict__ ws) {
    __shared__ float4 ms4[NTOT / 4];      // 32768
    __shared__ float4 seqbox[NFR];        // 128
    __shared__ float ssc[NTOT];           // 32768
    __shared__ u32 csr[NROW];             // 28672
    __shared__ u32 clsb7[7][3][32];       // 2688
    __shared__ u16 pool[OVTOT * PSTRIDE]; // 32768
    __shared__ u8 cls8[NTOT];             // 8192
    __shared__ u32 cnt_sh[8];
    __shared__ float redv[8];
    __shared__ int   redi[8];
    __shared__ int   sel_sh[NFR];
    __shared__ int   seqcls[NFR];
    __shared__ int   valid_sh, done_sh;
    __shared__ u16 ovl[OVTOT];
    __shared__ u8  ovact[OVTOT];

    float* ms = (float*)ms4;
    const int t = threadIdx.x, gw = t >> 6, ln = t & 63;
    const int sg = (gw << 3) + (ln >> 3), sl = ln & 7;   // subwave-8 id/lane

    // ---- reload adjacency state from workspace (coalesced) ----
    for (int idx = t; idx < NROW; idx += 512) csr[idx] = ws[idx];
    u32* p32 = (u32*)pool;
    for (int idx = t; idx < OVTOT * PSTRIDE / 2; idx += 512) p32[idx] = ws[WS_POOL + idx];
    if (t < 128) ((u32*)ovl)[t] = ws[WS_OVL + t];
    if (t < 7) cnt_sh[t] = ws[WS_OST2 + t];
    if (t < OVTOT) ovact[t] = 1;
    if (t == 0) { done_sh = 0; valid_sh = 0; }

    // ---- per-column registers + identity output + LDS copies ----
    float psc2[2][NFR]; u32 pclp[2] = {0u, 0u};
    #pragma unroll
    for (int f = 0; f < NFR; ++f) {
        #pragma unroll
        for (int c = 0; c < 2; ++c) {
            int i = t + (c << 9);
            float s = scores[f * NBX + i];
            int cl = classes[f * NBX + i];
            psc2[c][f] = s;
            pclp[c] |= (u32)cl << (3 * f);
            out[f * NBX + i] = s;           // identity part of reference output
            ssc[f * NBX + i] = s;
            cls8[f * NBX + i] = (u8)cl;
        }
    }
    // ---- class bitplanes (needed only for rare rescan paths) ----
    if (t < 224) {
        int fr = (t >> 5) + 1, w = t & 31;
        u32 p0 = 0, p1 = 0, p2 = 0;
        for (int b = 0; b < 32; ++b) {
            int c = classes[fr * NBX + w * 32 + b];
            p0 |= (u32)(c & 1) << b;
            p1 |= (u32)((c >> 1) & 1) << b;
            p2 |= (u32)((c >> 2) & 1) << b;
        }
        clsb7[fr - 1][0][w] = p0; clsb7[fr - 1][1][w] = p1; clsb7[fr - 1][2][w] = p2;
    }
    __syncthreads();

    // ---- iteration-invariant registers ----
    u32 pc2[2][7]; u32 lmask = 0;
    #pragma unroll
    for (int c = 0; c < 2; ++c) {
        #pragma unroll
        for (int f = 0; f < 7; ++f) {
            u32 p = csr[f * NBX + t + (c << 9)];
            pc2[c][f] = p;
            if ((p >> 30) == 3u && (p & 1023) == ((p >> 10) & 1023) && (p & 1023) != 1023)
                lmask |= 1u << (8 * c + f);     // listed: phase B owns the ms write
        }
    }
    int ose[7];                             // wave-uniform listed-range ends
    #pragma unroll
    for (int f = 0; f < 7; ++f) {
        int cv = (int)cnt_sh[f]; if (cv > OVPF) cv = OVPF;
        ose[f] = __builtin_amdgcn_readfirstlane(f * OVPF + cv);
    }
    u32 act = 0xFFFFu;                      // bit (8c+f) = active(f, col c)
    float ms7_0 = psc2[0][7], ms7_1 = psc2[1][7];
    ms[7 * NBX + t] = ms7_0;
    ms[7 * NBX + t + 512] = ms7_1;
    __syncthreads();

    // ---- 48 greedy extractions, 9 barriers each ----
    for (int it = 0; it < MAXS; ++it) {
        float bv = ms7_0; int bi = 7 * NBX + t;
        { float v = ms7_1; int r = 7 * NBX + t + 512;
          if (v > bv || (v == bv && r < bi)) { bv = v; bi = r; } }
        #pragma unroll
        for (int f = 6; f >= 0; --f) {
            const float* msn = &ms[(f + 1) * NBX];
            #pragma unroll
            for (int c = 0; c < 2; ++c) {
                const u32 p = pc2[c][f];
                const u32 cA = p >> 30, j0 = p & 1023, j1 = (p >> 10) & 1023;
                const bool ovf = (cA == 3u) && (j0 == j1);
                const int i = t + (c << 9);
                const int r = f * NBX + i;
                if (!ovf) {                          // inline rows (vast majority)
                    float v = NEGV;
                    if ((act >> (8 * c + f)) & 1) {
                        float best = 0.0f;           // == ref max(where(eff, ms_next, 0))
                        if (cA >= 1) best = fmaxf(best, fmaxf(msn[j0], 0.0f));
                        if (cA >= 2) best = fmaxf(best, fmaxf(msn[j1], 0.0f));
                        if (cA >= 3) best = fmaxf(best, fmaxf(msn[(p >> 20) & 1023], 0.0f));
                        v = __fadd_rn(psc2[c][f], best);
                    }
                    ms[r] = v;
                    if (v > bv || (v == bv && r < bi)) { bv = v; bi = r; }
                } else if (j0 == 1023) {             // rescan (budget exhausted; ~never)
                    float v = NEGV;
                    if ((act >> (8 * c + f)) & 1) {
                        float best = 0.0f;
                        int ca = (int)((pclp[c] >> (3 * f)) & 7u);
                        float4 a4 = gbox[r];
                        for (int w = 0; w < 32; ++w) {
                            u32 q0 = clsb7[f][0][w], q1 = clsb7[f][1][w], q2 = clsb7[f][2][w];
                            u32 m = ((ca & 1) ? q0 : ~q0) & ((ca & 2) ? q1 : ~q1) & ((ca & 4) ? q2 : ~q2);
                            while (m) {
                                int b = __ffs(m) - 1;
                                m &= m - 1;
                                int j = w * 32 + b;
                                float mv = msn[j];
                                if (mv > 0.0f && iou_ge(a4, gbox[(f + 1) * NBX + j]))
                                    best = fmaxf(best, mv);
                            }
                        }
                        v = __fadd_rn(psc2[c][f], best);
                    }
                    ms[r] = v;
                    if (v > bv || (v == bv && r < bi)) { bv = v; bi = r; }
                }
            }
            // phase B: listed rows, one 8-lane subgroup each; sl==0 lane merges
            // (v, rr) into its register argmax (associative fold -> no fix-up)
            {
                const int s1 = ose[f];
                for (int s = f * OVPF + sg; s < s1; s += 64) {
                    int i = ovl[s];
                    int rr = f * NBX + i;
                    bool actv = ovact[s] != 0;       // subgroup-uniform
                    float best = 0.0f;
                    if (actv) {
                        int deg = (int)pool[s * PSTRIDE];
                        if (deg != (int)DEG_RECOMP) {
                            for (int q = sl; q < deg; q += 8)
                                best = fmaxf(best, fmaxf(msn[pool[s * PSTRIDE + 1 + q]], 0.0f));
                        } else {                     // deg>63: recompute, 4 words/lane
                            int ca = (int)cls8[rr]; float4 a4 = gbox[rr];
                            for (int ww = 0; ww < 4; ++ww) {
                                int w = sl * 4 + ww;
                                u32 q0 = clsb7[f][0][w], q1 = clsb7[f][1][w], q2 = clsb7[f][2][w];
                                u32 m = ((ca & 1) ? q0 : ~q0) & ((ca & 2) ? q1 : ~q1) & ((ca & 4) ? q2 : ~q2);
                                while (m) {
                                    int b = __ffs(m) - 1;
                                    m &= m - 1;
                                    int j = w * 32 + b;
                                    if (iou_ge(a4, gbox[(f + 1) * NBX + j]))
                                        best = fmaxf(best, fmaxf(msn[j], 0.0f));
                                }
                            }
                        }
                        best = fmaxf(best, __shfl_xor(best, 1));
                        best = fmaxf(best, __shfl_xor(best, 2));
                        best = fmaxf(best, __shfl_xor(best, 4));
                    }
                    if (sl == 0) {
                        float v = actv ? __fadd_rn(ssc[rr], best) : NEGV;
                        ms[rr] = v;
                        if (v > bv || (v == bv && rr < bi)) { bv = v; bi = rr; }
                    }
                }
            }
            if (f == 0) {   // fold wave argmax reduce before the trailing barrier
                #pragma unroll
                for (int off = 32; off > 0; off >>= 1) {
                    float ov = __shfl_down(bv, off); int oi = __shfl_down(bi, off);
                    if (ov > bv || (ov == bv && oi < bi)) { bv = ov; bi = oi; }
                }
                if (ln == 0) { redv[gw] = bv; redi[gw] = bi; }
            }
            __syncthreads();                          // barriers 1..7
        }

        // ---- wave 0: final reduce + traceback + stats + out + valid/done ----
        if (t < 64) {
            float v = (ln < 8) ? redv[ln] : -3.0e38f;
            int i0 = (ln < 8) ? redi[ln] : 0x7fffffff;
            #pragma unroll
            for (int off = 4; off > 0; off >>= 1) {
                float ov = __shfl_down(v, off); int oi = __shfl_down(i0, off);
                if (ov > v || (ov == v && oi < i0)) { v = ov; i0 = oi; }
            }
            v = __shfl(v, 0); i0 = __shfl(i0, 0);
            const float bestval = v;
            const int fstar = i0 >> 10, istar = i0 & (NBX - 1);
            if (ln < NFR) sel_sh[ln] = -1;
            int cur = istar;
            for (int f = fstar; f < NFR; ++f) {       // all breaks wave-uniform
                if (ln == 0) sel_sh[f] = cur;
                if (f == 7) break;                    // adj_pad[7] all-zero
                u32 p = csr[f * NBX + cur];
                u32 c = p >> 30, j0 = p & 1023, j1 = (p >> 10) & 1023;
                const float* msn = &ms[(f + 1) * NBX];
                if (!((c == 3u) && (j0 == j1))) {     // inline: all-lane redundant
                    float tb = -3.0e38f; int tj = -1; // ascending j + strict >
                    if (c >= 1) { float m = msn[j0]; if (m != NEGV) { tb = m; tj = (int)j0; } }
                    if (c >= 2) { float m = msn[j1]; if (m != NEGV && m > tb) { tb = m; tj = (int)j1; } }
                    if (c >= 3) { int j2 = (p >> 20) & 1023; float m = msn[j2];
                                  if (m != NEGV && m > tb) { tb = m; tj = j2; } }
                    if (tj < 0) break;                // !has_link
                    cur = tj;
                } else {                              // listed / rescan: cooperative
                    float tv = -3.0e38f; int tj = 0x7fffffff;
                    bool recomp = true;
                    if (j0 != 1023) {
                        int s = (int)j0;
                        int deg = (int)pool[s * PSTRIDE];
                        if (deg != (int)DEG_RECOMP) {
                            recomp = false;
                            for (int q = ln; q < deg; q += 64) {
                                int j = (int)pool[s * PSTRIDE + 1 + q];
                                float m = msn[j];
                                if (m != NEGV && (m > tv || (m == tv && j < tj))) { tv = m; tj = j; }
                            }
                        }
                    }
                    if (recomp) {
                        int ca = (int)cls8[f * NBX + cur]; float4 a4 = gbox[f * NBX + cur];
                        if (ln < 32) {
                            u32 q0 = clsb7[f][0][ln], q1 = clsb7[f][1][ln], q2 = clsb7[f][2][ln];
                            u32 m = ((ca & 1) ? q0 : ~q0) & ((ca & 2) ? q1 : ~q1) & ((ca & 4) ? q2 : ~q2);
                            while (m) {
                                int b = __ffs(m) - 1;
                                m &= m - 1;
                                int j = ln * 32 + b;
                                float mv = msn[j];
                                if (mv != NEGV && iou_ge(a4, gbox[(f + 1) * NBX + j])) {
                                    if (mv > tv || (mv == tv && j < tj)) { tv = mv; tj = j; }
                                }
                            }
                        }
                    }
                    #pragma unroll
                    for (int off = 32; off > 0; off >>= 1) {
                        float ov = __shfl_down(tv, off); int oj = __shfl_down(tj, off);
                        if (ov > tv || (ov == tv && oj < tj)) { tv = ov; tj = oj; }
                    }
                    tv = __shfl(tv, 0); tj = __shfl(tj, 0);
                    if (tv < -1.0e37f) break;         // !has_link
                    cur = tj;
                }
            }
            // stats (avg is output-only; len/bestval steering is exact)
            float sv = 0.0f; int cc = 0;
            if (ln < NFR) {
                int sj = sel_sh[ln];
                if (sj >= 0) {
                    sv = ssc[(ln << 10) + sj]; cc = 1;
                    seqbox[ln] = gbox[(ln << 10) + sj];
                    seqcls[ln] = (int)cls8[(ln << 10) + sj];
                }
            }
            #pragma unroll
            for (int off = 4; off > 0; off >>= 1) {
                sv = __fadd_rn(sv, __shfl_down(sv, off));
                cc += __shfl_down(cc, off);
            }
            sv = __shfl(sv, 0); cc = __shfl(cc, 0);
            int dprev = done_sh;                      // read precedes lane-0 write
            float avg = __fdiv_rn(sv, (float)cc);     // cc >= 1 always
            bool ok = (cc > 1) && (bestval > 0.0f);
            int validf = (ok && !dprev) ? 1 : 0;
            if (ln == 0) { valid_sh = validf; if (!ok) done_sh = 1; }
            if (validf && ln < NFR) {
                int sj = sel_sh[ln];
                if (sj >= 0) out[ln * NBX + sj] = avg;
            }
        }
        __syncthreads();                              // barrier 8

        // ---- suppression + state publish (fenced; only when valid) ----
        if (valid_sh) {
            #pragma unroll
            for (int f = 0; f < NFR; ++f) {
                int sj = sel_sh[f];
                if (sj < 0) continue;                 // frame_in false
                int scl = seqcls[f];
                float4 sb = seqbox[f];
                #pragma unroll
                for (int c = 0; c < 2; ++c) {
                    int cl = (int)((pclp[c] >> (3 * f)) & 7u);
                    if (cl != scl) continue;
                    float4 b = gbox[f * NBX + t + (c << 9)];   // L1/L2-hot
                    if (iou_ge(sb, b)) act &= ~(1u << (8 * c + f));
                }
            }
            #pragma unroll
            for (int c = 0; c < 2; ++c) {
                #pragma unroll
                for (int f = 0; f < 7; ++f) if ((lmask >> (8 * c + f)) & 1)
                    ovact[pc2[c][f] & 1023] = (u8)((act >> (8 * c + f)) & 1); // unique owner
            }
            ms7_0 = ((act >> 7) & 1) ? psc2[0][7] : NEGV;
            ms7_1 = ((act >> 15) & 1) ? psc2[1][7] : NEGV;
            ms[7 * NBX + t] = ms7_0;                  // next iteration's DP init
            ms[7 * NBX + t + 512] = ms7_1;
        }
        __syncthreads();                              // barrier 9
        if (done_sh) break;   // uniform; remaining reference iterations are no-ops
    }
}

// ================== fallback: verified round-2 monolith ==================
#define OVTOTF 256
#define ENC_PENDING ((3u << 30) | (1022u << 10) | 1022u)
__global__ __launch_bounds__(1024) void seqnms_full(const float4* __restrict__ gbox,
                                                    const float* __restrict__ scores,
                                                    const int* __restrict__ classes,
                                                    float* __restrict__ out) {
    __shared__ float4 ms4[NTOT / 4];
    __shared__ float4 seqbox[NFR];
    __shared__ float ssc[NTOT];
    __shared__ u32 csr[NROW];
    __shared__ u32 clsb7[7][3][32];
    __shared__ u16 pool[OVTOTF * PSTRIDE];
    __shared__ u8 cls8[NTOT];
    __shared__ u32 ostart[8];
    __shared__ u32 ofill[7];
    __shared__ u32 ocnt[7];
    __shared__ float redv[16];
    __shared__ int   redi[16];
    __shared__ int   sel_sh[NFR];
    __shared__ int   seqcls[NFR];
    __shared__ float avg_sh;
    __shared__ int   valid_sh, done_sh;
    __shared__ u16 ovl[OVTOTF];
    __shared__ u8  ovact[OVTOTF];

    float* ms = (float*)ms4;
    const int t = threadIdx.x, gw = t >> 6, ln = t & 63;

    float psc[NFR]; int pcl[NFR]; float4 pbx[NFR];
    #pragma unroll
    for (int f = 0; f < NFR; ++f) {
        psc[f] = scores[f * NBX + t];
        pcl[f] = classes[f * NBX + t];
        pbx[f] = gbox[f * NBX + t];
        out[f * NBX + t] = psc[f];
        ssc[f * NBX + t] = psc[f];
        cls8[f * NBX + t] = (u8)pcl[f];
    }
    if (t < 7) { ocnt[t] = 0; ofill[t] = 0; }
    if (t < OVTOTF) ovact[t] = 1;
    if (t == 0) done_sh = 0;

    if (t < 224) {
        int fr = (t >> 5) + 1, w = t & 31;
        u32 p0 = 0, p1 = 0, p2 = 0;
        for (int b = 0; b < 32; ++b) {
            int c = classes[fr * NBX + w * 32 + b];
            p0 |= (u32)(c & 1) << b;
            p1 |= (u32)((c >> 1) & 1) << b;
            p2 |= (u32)((c >> 2) & 1) << b;
        }
        clsb7[fr - 1][0][w] = p0; clsb7[fr - 1][1][w] = p1; clsb7[fr - 1][2][w] = p2;
    }
    __syncthreads();

    for (int f = 0; f < 7; ++f) {
        ms4[t] = pbx[f + 1];
        __syncthreads();
        const int r = f * NBX + t;
        const int ca = pcl[f];
        const float4 a4 = pbx[f];
        u32 cnt = 0, j0 = 0, j1 = 0, j2 = 0;
        for (int w = 0; w < 32; ++w) {
            u32 q0 = clsb7[f][0][w], q1 = clsb7[f][1][w], q2 = clsb7[f][2][w];
            u32 m = ((ca & 1) ? q0 : ~q0) & ((ca & 2) ? q1 : ~q1) & ((ca & 4) ? q2 : ~q2);
            while (m) {
                int b = __ffs(m) - 1;
                m &= m - 1;
                int j = w * 32 + b;
                if (iou_ge(a4, ms4[j])) {
                    if (cnt == 0) j0 = j; else if (cnt == 1) j1 = j; else if (cnt == 2) j2 = j;
                    ++cnt;
                }
            }
        }
        if (cnt <= 3) csr[r] = (cnt << 30) | (j2 << 20) | (j1 << 10) | j0;
        else { atomicAdd(&ocnt[f], 1u); csr[r] = ENC_PENDING; }
        __syncthreads();
    }
    if (t == 0) {
        u32 s = 0;
        for (int f = 0; f < 7; ++f) { ostart[f] = s; s += ocnt[f]; }
        ostart[7] = s;
    }
    __syncthreads();
    for (int f = 0; f < 7; ++f) {
        int r = f * NBX + t;
        if (csr[r] == ENC_PENDING) {
            u32 slot = ostart[f] + atomicAdd(&ofill[f], 1u);
            if (slot < OVTOTF) { ovl[slot] = (u16)t; csr[r] = (3u << 30) | (slot << 10) | slot; }
            else csr[r] = ENC_RESCAN;
        }
    }
    __syncthreads();
    {
        int total = (int)ostart[7]; if (total > OVTOTF) total = OVTOTF;
        for (int s = gw; s < total; s += 16) {
            int f = 0;
            while (s >= (int)ostart[f + 1]) ++f;
            int i = ovl[s];
            int ca = (int)cls8[f * NBX + i];
            float4 a4 = gbox[f * NBX + i];
            u32 mym = 0;
            if (ln < 32) {
                u32 q0 = clsb7[f][0][ln], q1 = clsb7[f][1][ln], q2 = clsb7[f][2][ln];
                u32 m = ((ca & 1) ? q0 : ~q0) & ((ca & 2) ? q1 : ~q1) & ((ca & 4) ? q2 : ~q2);
                while (m) {
                    int b = __ffs(m) - 1;
                    m &= m - 1;
                    if (iou_ge(a4, gbox[(f + 1) * NBX + ln * 32 + b])) mym |= 1u << b;
                }
            }
            int c = __popc(mym), inc = c;
            for (int off = 1; off < 64; off <<= 1) {
                int v = __shfl_up(inc, off);
                if (ln >= off) inc += v;
            }
            int deg = __shfl(inc, 63);
            int base = inc - c;
            if (deg <= PSTRIDE - 1) {
                if (ln == 0) pool[s * PSTRIDE] = (u16)deg;
                if (ln < 32) {
                    u32 m = mym; int idx = base;
                    while (m) {
                        int b = __ffs(m) - 1;
                        m &= m - 1;
                        pool[s * PSTRIDE + 1 + idx++] = (u16)(ln * 32 + b);
                    }
                }
            } else if (ln == 0) pool[s * PSTRIDE] = (u16)DEG_RECOMP;
        }
    }
    __syncthreads();

    u32 pc[7]; u32 lmask = 0;
    #pragma unroll
    for (int f = 0; f < 7; ++f) {
        u32 p = csr[f * NBX + t];
        pc[f] = p;
        if ((p >> 30) == 3u && (p & 1023) == ((p >> 10) & 1023) && (p & 1023) != 1023)
            lmask |= 1u << f;
    }
    int os[8];
    #pragma unroll
    for (int f = 0; f < 8; ++f) {
        int v = (int)ostart[f]; if (v > OVTOTF) v = OVTOTF;
        os[f] = __builtin_amdgcn_readfirstlane(v);
    }
    u32 act = 0xFF;
    float ms7 = psc[7];
    ms[7 * NBX + t] = ms7;
    __syncthreads();

    for (int it = 0; it < MAXS; ++it) {
        float bv = ms7; int bi = 7 * NBX + t;
        #pragma unroll
        for (int f = 6; f >= 0; --f) {
            const float* msn = &ms[(f + 1) * NBX];
            const u32 p = pc[f];
            const u32 c = p >> 30, j0 = p & 1023, j1 = (p >> 10) & 1023;
            const bool ovf = (c == 3u) && (j0 == j1);
            const int r = f * NBX + t;
            if (!ovf) {
                float v = NEGV;
                if ((act >> f) & 1) {
                    float best = 0.0f;
                    if (c >= 1) best = fmaxf(best, fmaxf(msn[j0], 0.0f));
                    if (c >= 2) best = fmaxf(best, fmaxf(msn[j1], 0.0f));
                    if (c >= 3) best = fmaxf(best, fmaxf(msn[(p >> 20) & 1023], 0.0f));
                    v = __fadd_rn(psc[f], best);
                }
                ms[r] = v;
                if (v > bv || (v == bv && r < bi)) { bv = v; bi = r; }
            } else if (j0 == 1023) {
                float v = NEGV;
                if ((act >> f) & 1) {
                    float best = 0.0f;
                    int ca = pcl[f]; float4 a4 = pbx[f];
                    for (int w = 0; w < 32; ++w) {
                        u32 q0 = clsb7[f][0][w], q1 = clsb7[f][1][w], q2 = clsb7[f][2][w];
                        u32 m = ((ca & 1) ? q0 : ~q0) & ((ca & 2) ? q1 : ~q1) & ((ca & 4) ? q2 : ~q2);
                        while (m) {
                            int b = __ffs(m) - 1;
                            m &= m - 1;
                            int j = w * 32 + b;
                            float mv = msn[j];
                            if (mv > 0.0f && iou_ge(a4, gbox[(f + 1) * NBX + j]))
                                best = fmaxf(best, mv);
                        }
                    }
                    v = __fadd_rn(psc[f], best);
                }
                ms[r] = v;
                if (v > bv || (v == bv && r < bi)) { bv = v; bi = r; }
            }
            {
                const int s1 = os[f + 1];
                for (int s = os[f] + gw; s < s1; s += 16) {
                    int i = ovl[s];
                    int rr = f * NBX + i;
                    bool actv = ovact[s] != 0;
                    float best = 0.0f;
                    if (actv) {
                        int deg = (int)pool[s * PSTRIDE];
                        if (deg != (int)DEG_RECOMP) {
                            for (int q = ln; q < deg; q += 64)
                                best = fmaxf(best, fmaxf(msn[pool[s * PSTRIDE + 1 + q]], 0.0f));
                        } else {
                            int ca = (int)cls8[rr]; float4 a4 = gbox[rr];
                            if (ln < 32) {
                                u32 q0 = clsb7[f][0][ln], q1 = clsb7[f][1][ln], q2 = clsb7[f][2][ln];
                                u32 m = ((ca & 1) ? q0 : ~q0) & ((ca & 2) ? q1 : ~q1) & ((ca & 4) ? q2 : ~q2);
                                while (m) {
                                    int b = __ffs(m) - 1;
                                    m &= m - 1;
                                    int j = ln * 32 + b;
                                    if (iou_ge(a4, gbox[(f + 1) * NBX + j]))
                                        best = fmaxf(best, fmaxf(msn[j], 0.0f));
                                }
                            }
                        }
                        #pragma unroll
                        for (int off = 32; off > 0; off >>= 1)
                            best = fmaxf(best, __shfl_down(best, off));
                    }
                    if (ln == 0) ms[rr] = actv ? __fadd_rn(ssc[rr], best) : NEGV;
                }
            }
            __syncthreads();
        }

        #pragma unroll
        for (int f = 0; f < 7; ++f) if ((lmask >> f) & 1) {
            int r = f * NBX + t; float v = ms[r];
            if (v > bv || (v == bv && r < bi)) { bv = v; bi = r; }
        }
        #pragma unroll
        for (int off = 32; off > 0; off >>= 1) {
            float ov = __shfl_down(bv, off); int oi = __shfl_down(bi, off);
            if (ov > bv || (ov == bv && oi < bi)) { bv = ov; bi = oi; }
        }
        if (ln == 0) { redv[gw] = bv; redi[gw] = bi; }
        __syncthreads();

        if (t < 64) {
            float v = (ln < 16) ? redv[ln] : -3.0e38f;
            int i0 = (ln < 16) ? redi[ln] : 0x7fffffff;
            #pragma unroll
            for (int off = 8; off > 0; off >>= 1) {
                float ov = __shfl_down(v, off); int oi = __shfl_down(i0, off);
                if (ov > v || (ov == v && oi < i0)) { v = ov; i0 = oi; }
            }
            v = __shfl(v, 0); i0 = __shfl(i0, 0);
            const float bestval = v;
            const int fstar = i0 >> 10, istar = i0 & (NBX - 1);
            if (ln < NFR) sel_sh[ln] = -1;
            int cur = istar;
            for (int f = fstar; f < NFR; ++f) {
                if (ln == 0) sel_sh[f] = cur;
                if (f == 7) break;
                u32 p = csr[f * NBX + cur];
                u32 c = p >> 30, j0 = p & 1023, j1 = (p >> 10) & 1023;
                const float* msn = &ms[(f + 1) * NBX];
                if (!((c == 3u) && (j0 == j1))) {
                    float tb = -3.0e38f; int tj = -1;
                    if (c >= 1) { float m = msn[j0]; if (m != NEGV) { tb = m; tj = (int)j0; } }
                    if (c >= 2) { float m = msn[j1]; if (m != NEGV && m > tb) { tb = m; tj = (int)j1; } }
                    if (c >= 3) { int j2 = (p >> 20) & 1023; float m = msn[j2];
                                  if (m != NEGV && m > tb) { tb = m; tj = j2; } }
                    if (tj < 0) break;
                    cur = tj;
                } else {
                    float tv = -3.0e38f; int tj = 0x7fffffff;
                    bool recomp = true;
                    if (j0 != 1023) {
                        int s = (int)j0;
                        int deg = (int)pool[s * PSTRIDE];
                        if (deg != (int)DEG_RECOMP) {
                            recomp = false;
                            for (int q = ln; q < deg; q += 64) {
                                int j = (int)pool[s * PSTRIDE + 1 + q];
                                float m = msn[j];
                                if (m != NEGV && (m > tv || (m == tv && j < tj))) { tv = m; tj = j; }
                            }
                        }
                    }
                    if (recomp) {
                        int ca = (int)cls8[f * NBX + cur]; float4 a4 = gbox[f * NBX + cur];
                        if (ln < 32) {
                            u32 q0 = clsb7[f][0][ln], q1 = clsb7[f][1][ln], q2 = clsb7[f][2][ln];
                            u32 m = ((ca & 1) ? q0 : ~q0) & ((ca & 2) ? q1 : ~q1) & ((ca & 4) ? q2 : ~q2);
                            while (m) {
                                int b = __ffs(m) - 1;
                                m &= m - 1;
                                int j = ln * 32 + b;
                                float mv = msn[j];
                                if (mv != NEGV && iou_ge(a4, gbox[(f + 1) * NBX + j])) {
                                    if (mv > tv || (mv == tv && j < tj)) { tv = mv; tj = j; }
                                }
                            }
                        }
                    }
                    #pragma unroll
                    for (int off = 32; off > 0; off >>= 1) {
                        float ov = __shfl_down(tv, off); int oj = __shfl_down(tj, off);
                        if (ov > tv || (ov == tv && oj < tj)) { tv = ov; tj = oj; }
                    }
                    tv = __shfl(tv, 0); tj = __shfl(tj, 0);
                    if (tv < -1.0e37f) break;
                    cur = tj;
                }
            }
            float sv = 0.0f; int cc = 0;
            if (ln < NFR) {
                int sj = sel_sh[ln];
                if (sj >= 0) {
                    sv = ssc[ln * NBX + sj]; cc = 1;
                    seqbox[ln] = gbox[ln * NBX + sj];
                    seqcls[ln] = (int)cls8[ln * NBX + sj];
                }
            }
            #pragma unroll
            for (int off = 4; off > 0; off >>= 1) {
                sv = __fadd_rn(sv, __shfl_down(sv, off));
                cc += __shfl_down(cc, off);
            }
            if (ln == 0) {
                avg_sh = __fdiv_rn(sv, (float)cc);
                bool ok = (cc > 1) && (bestval > 0.0f);
                valid_sh = (ok && !done_sh) ? 1 : 0;
                if (!ok) done_sh = 1;
            }
        }
        __syncthreads();

        if (valid_sh) {
            #pragma unroll
            for (int f = 0; f < NFR; ++f) {
                int sj = sel_sh[f];
                if (sj < 0) continue;
                if (pcl[f] != seqcls[f]) continue;
                if (iou_ge(seqbox[f], pbx[f])) act &= ~(1u << f);
            }
            #pragma unroll
            for (int f = 0; f < 7; ++f) if ((lmask >> f) & 1)
                ovact[pc[f] & 1023] = (u8)((act >> f) & 1);
            ms7 = (act & 0x80) ? psc[7] : NEGV;
            ms[7 * NBX + t] = ms7;
            if (t < NFR) {
                int sj = sel_sh[t];
                if (sj >= 0) out[t * NBX + sj] = avg_sh;
            }
        }
        __syncthreads();
        if (done_sh) break;
    }
}

extern "C" void kernel_launch(void* const* d_in, const int* in_sizes, int n_in,
                              void* d_out, int out_size, void* d_ws, size_t ws_size,
                              hipStream_t stream) {
    const float4* boxes = (const float4*)d_in[0];     // (8,1024,4) float32
    const float* scores = (const float*)d_in[1];      // (8,1024) float32
    const int* classes = (const int*)d_in[2];         // (8,1024) int32
    float* out = (float*)d_out;                       // (8,1024) float32
    const int use_split =
        (d_ws != nullptr && ws_size >= (size_t)(WS_WORDS * 4)) ? 1 : 0;
    if (use_split) {
        seqnms_setup<<<7, 1024, 0, stream>>>(boxes, classes, (u32*)d_ws);
        seqnms_iter<<<1, 512, 0, stream>>>(boxes, scores, classes, out, (const u32*)d_ws);
    } else {
        seqnms_full<<<1, 1024, 0, stream>>>(boxes, scores, classes, out);
    }
}